// Round 7
// baseline (72.521 us; speedup 1.0000x reference)
//
#include <hip/hip_runtime.h>
#include <hip/hip_bf16.h>

#define BATCH 8
#define V 2048
#define H 256
#define D 128

typedef __attribute__((ext_vector_type(8))) short bf16x8;
typedef __attribute__((ext_vector_type(4))) float f32x4;

static __device__ __forceinline__ unsigned short bf16u(float f) {
  __hip_bfloat16 h = __float2bfloat16(f);
  unsigned short u;
  __builtin_memcpy(&u, &h, 2);
  return u;
}

// -------- K_pack: adj -> bitmask words [V][64]; plus W -> Wt (transpose) --------
__global__ __launch_bounds__(256) void k_pack(const int* __restrict__ adj,
                                              const float* __restrict__ W,
                                              unsigned int* __restrict__ pk,
                                              float* __restrict__ Wt) {
  const int blk = blockIdx.x;
  if (blk < V) {
    const int w = threadIdx.x >> 6, lane = threadIdx.x & 63;
    const int* row = adj + (size_t)blk * V;
#pragma unroll
    for (int it = 0; it < 8; ++it) {
      const int j = it * 256 + w * 64 + lane;
      unsigned long long m = __ballot(row[j] != 0);
      if (lane < 2)
        pk[blk * 64 + it * 8 + w * 2 + lane] = (unsigned int)(m >> (lane * 32));
    }
  } else {
    const int d = blk - V;  // 0..127
    Wt[(size_t)threadIdx.x * D + d] = W[(size_t)d * H + threadIdx.x];
  }
}

// -------- K_proj: p = x @ W^T (fp32), fused e_i + exp-factor tables + bf16 frag store --------
__global__ __launch_bounds__(256, 2) void k_proj(const float* __restrict__ x,
                                                 const float* __restrict__ Wt,
                                                 const float* __restrict__ a,
                                                 __hip_bfloat16* __restrict__ pTf,
                                                 float* __restrict__ ei,
                                                 float* __restrict__ Fj,
                                                 float* __restrict__ Fp) {
  __shared__ float xs[32 * H];            // 32 KB
  __shared__ __hip_bfloat16 st[128][52];  // 13 KB, padded
  const int t = threadIdx.x;
  const int b = blockIdx.x >> 6;
  const int j0 = (blockIdx.x & 63) * 32;
  {
    const float4* xsrc = (const float4*)(x + ((size_t)b * V + j0) * H);
    float4* xdst = (float4*)xs;
#pragma unroll
    for (int q = 0; q < 8; ++q) xdst[t + 256 * q] = xsrc[t + 256 * q];
  }
  __syncthreads();

  const int dq = t & 31;  // d quad: d = dq*4+dd
  const int jg = t >> 5;  // rows jg*4+k
  float acc[4][4];        // [k(row)][dd(col)]
#pragma unroll
  for (int k = 0; k < 4; ++k)
#pragma unroll
    for (int dd = 0; dd < 4; ++dd) acc[k][dd] = 0.f;

  const float* wbase = Wt + dq * 4;
  const float* xbase = xs + jg * 4 * H;
#pragma unroll 2
  for (int h4 = 0; h4 < 64; ++h4) {
    float4 wv[4], xv[4];
#pragma unroll
    for (int hh = 0; hh < 4; ++hh)
      wv[hh] = *(const float4*)(wbase + (size_t)(h4 * 4 + hh) * D);
#pragma unroll
    for (int k = 0; k < 4; ++k)
      xv[k] = *(const float4*)(xbase + k * H + h4 * 4);
#pragma unroll
    for (int k = 0; k < 4; ++k)
#pragma unroll
      for (int dd = 0; dd < 4; ++dd)
        acc[k][dd] += xv[k].x * ((const float*)&wv[0])[dd] +
                      xv[k].y * ((const float*)&wv[1])[dd] +
                      xv[k].z * ((const float*)&wv[2])[dd] +
                      xv[k].w * ((const float*)&wv[3])[dd];
  }

  // e_i / e_j from fp32 accumulators (reduce over dq lanes); store exp-factor tables
  const float4 aLv = *(const float4*)(a + dq * 4);
  const float4 aRv = *(const float4*)(a + D + dq * 4);
#pragma unroll
  for (int k = 0; k < 4; ++k) {
    float te = acc[k][0] * aLv.x + acc[k][1] * aLv.y + acc[k][2] * aLv.z + acc[k][3] * aLv.w;
    float tf = acc[k][0] * aRv.x + acc[k][1] * aRv.y + acc[k][2] * aRv.z + acc[k][3] * aRv.w;
#pragma unroll
    for (int off = 1; off < 32; off <<= 1) {
      te += __shfl_xor(te, off, 64);
      tf += __shfl_xor(tf, off, 64);
    }
    if (dq == 0) {
      const size_t row = (size_t)b * V + j0 + jg * 4 + k;
      ei[row] = te;
      Fj[row] = __expf(tf);
      Fp[row] = __expf(0.2f * tf);
    }
  }

  // bf16 transpose into st: st[d][j_local]
#pragma unroll
  for (int dd = 0; dd < 4; ++dd) {
    union { unsigned short u[4]; unsigned long long ll; } pk_;
#pragma unroll
    for (int k = 0; k < 4; ++k) pk_.u[k] = bf16u(acc[k][dd]);
    *(unsigned long long*)&st[dq * 4 + dd][jg * 4] = pk_.ll;
  }
  __syncthreads();

  // fragment store: pTf[b][c][dt][ks][lane][8]
  const int c = (blockIdx.x & 63) >> 1;
  const int ks = blockIdx.x & 1;
  const int lane = t & 63, g = t >> 6;
#pragma unroll
  for (int ff = 0; ff < 2; ++ff) {
    const int dt = ff * 4 + g;
    const int dR = dt * 16 + (lane & 15);
    const int jc = (lane >> 4) * 8;
    union { unsigned long long ll[2]; bf16x8 v; } vv_;
    vv_.ll[0] = *(const unsigned long long*)&st[dR][jc];
    vv_.ll[1] = *(const unsigned long long*)&st[dR][jc + 4];
    *(bf16x8*)((char*)pTf +
               (((((size_t)b * 32 + c) * 8 + dt) * 2 + ks) * 64 + lane) * 16) = vv_.v;
  }
}

// -------- K_attn: out = relu((w @ p) / rowsum) via MFMA --------
// NO LDS, NO barriers: each wave loads B fragments directly from global
// (coalesced dwordx4, register double-buffer, 1-iter prefetch lead; the 8
// co-resident waves per CU read identical chunks -> L1/L2 dedup).
// w = max(Ei*Fj, Eip*Pj) (exact lrelu-exp factorization);
// bf16 pack via v_cvt_pk_bf16_f32.

#define CVTPK(dst, lo, hi) \
  asm("v_cvt_pk_bf16_f32 %0, %1, %2" : "=v"(dst) : "v"(lo), "v"(hi));

#define WGEN(AF, FA, FB, PA, PB, AW)                                   \
  {                                                                    \
    const unsigned int sh_ = (AW) >> kq8;                              \
    float vv[8];                                                       \
    _Pragma("unroll") for (int e_ = 0; e_ < 4; ++e_) {                 \
      const float w_ = fmaxf(Ei * ((const float*)&(FA))[e_],           \
                             Eip * ((const float*)&(PA))[e_]);         \
      const int m_ = ((int)(sh_ << (31 - e_))) >> 31;                  \
      vv[e_] = __int_as_float(__float_as_int(w_) & m_);                \
    }                                                                  \
    _Pragma("unroll") for (int e_ = 0; e_ < 4; ++e_) {                 \
      const float w_ = fmaxf(Ei * ((const float*)&(FB))[e_],           \
                             Eip * ((const float*)&(PB))[e_]);         \
      const int m_ = ((int)(sh_ << (27 - e_))) >> 31;                  \
      vv[4 + e_] = __int_as_float(__float_as_int(w_) & m_);            \
    }                                                                  \
    rsum += ((vv[0] + vv[1]) + (vv[2] + vv[3])) +                      \
            ((vv[4] + vv[5]) + (vv[6] + vv[7]));                       \
    CVTPK(AF.u[0], vv[0], vv[1])                                       \
    CVTPK(AF.u[1], vv[2], vv[3])                                       \
    CVTPK(AF.u[2], vv[4], vv[5])                                       \
    CVTPK(AF.u[3], vv[6], vv[7])                                       \
  }

// load chunk C's 8 B-fragments (8 x 16B per lane) straight into regs
#define LOADB(BR, C)                                                   \
  {                                                                    \
    const char* g_ = gbase + (size_t)(C) * 16384;                      \
    _Pragma("unroll") for (int q_ = 0; q_ < 8; ++q_)                   \
      BR[q_] = *(const bf16x8*)(g_ + q_ * 1024);                       \
  }

// prefetch F/P/adj for chunk C
#define PFETCH(FA, FB, F1A, F1B, PA, PB, P1A, P1B, W0, W1, C)  \
  {                                                            \
    const float* fp_ = Fb + (C) * 64 + kq8;                    \
    const float* pp_ = Pb + (C) * 64 + kq8;                    \
    FA = *(const float4*)fp_;        FB = *(const float4*)(fp_ + 4);  \
    F1A = *(const float4*)(fp_ + 32); F1B = *(const float4*)(fp_ + 36); \
    PA = *(const float4*)pp_;        PB = *(const float4*)(pp_ + 4);  \
    P1A = *(const float4*)(pp_ + 32); P1B = *(const float4*)(pp_ + 36); \
    W0 = adjp[iR * 64 + (C) * 2];                              \
    W1 = adjp[iR * 64 + (C) * 2 + 1];                          \
  }

// consume set X (chunk C), then refill X with chunk C+2
#define BODY(C, BX, FA, FB, F1A, F1B, PA, PB, P1A, P1B, W0, W1)          \
  {                                                                      \
    union U_ { unsigned int u[4]; bf16x8 v; } af0, af1;                  \
    WGEN(af0, FA, FB, PA, PB, W0)                                        \
    WGEN(af1, F1A, F1B, P1A, P1B, W1)                                    \
    _Pragma("unroll") for (int nt = 0; nt < 4; ++nt) {                   \
      acc[nt] = __builtin_amdgcn_mfma_f32_16x16x32_bf16(af0.v, BX[nt * 2], acc[nt], 0, 0, 0); \
      acc[nt] = __builtin_amdgcn_mfma_f32_16x16x32_bf16(af1.v, BX[nt * 2 + 1], acc[nt], 0, 0, 0); \
    }                                                                    \
    if ((C) < 30) {                                                      \
      LOADB(BX, (C) + 2)                                                 \
      PFETCH(FA, FB, F1A, F1B, PA, PB, P1A, P1B, W0, W1, (C) + 2)        \
    }                                                                    \
  }

__global__ __launch_bounds__(256, 2) void k_attn(
    const __hip_bfloat16* __restrict__ pTf,
    const float* __restrict__ ei, const float* __restrict__ Fjt,
    const float* __restrict__ Fpt,
    const unsigned int* __restrict__ adjp,
    float* __restrict__ out) {
  const int t = threadIdx.x, lane = t & 63, wave = t >> 6;
  // bijective XCD chunk swizzle (nwg=512, 64 per XCD)
  const int pay = (blockIdx.x & 7) * 64 + (blockIdx.x >> 3);
  const int bdh = pay >> 5;
  const int ig = pay & 31;
  const int b = bdh >> 1, dh = bdh & 1;
  const int i0 = ig * 64 + wave * 16;
  const int kq = lane >> 4;
  const int kq8 = kq * 8;
  const int iR = i0 + (lane & 15);
  const float eiv = ei[(size_t)b * V + iR];
  const float Ei = __expf(eiv);
  const float Eip = __expf(0.2f * eiv);
  const float* Fb = Fjt + (size_t)b * V;
  const float* Pb = Fpt + (size_t)b * V;
  const size_t fb0 = ((size_t)b * 32) * 16384 + (size_t)dh * 8192;
  const char* gbase = (const char*)pTf + fb0 + lane * 16;

  f32x4 acc[4];
#pragma unroll
  for (int nt = 0; nt < 4; ++nt) acc[nt] = (f32x4){0.f, 0.f, 0.f, 0.f};
  float rsum = 0.f;

  // register double-buffers: set A = even chunks, set B = odd chunks
  bf16x8 bA[8], bB[8];
  float4 fAa, fAb, fA1a, fA1b, pAa, pAb, pA1a, pA1b;
  float4 fBa, fBb, fB1a, fB1b, pBa, pBb, pB1a, pB1b;
  unsigned int wA0, wA1, wB0, wB1;

  LOADB(bA, 0)
  PFETCH(fAa, fAb, fA1a, fA1b, pAa, pAb, pA1a, pA1b, wA0, wA1, 0)
  LOADB(bB, 1)
  PFETCH(fBa, fBb, fB1a, fB1b, pBa, pBb, pB1a, pB1b, wB0, wB1, 1)

  for (int c2 = 0; c2 < 16; ++c2) {
    const int c = c2 * 2;
    BODY(c,     bA, fAa, fAb, fA1a, fA1b, pAa, pAb, pA1a, pA1b, wA0, wA1)
    BODY(c + 1, bB, fBa, fBb, fB1a, fB1b, pBa, pBb, pB1a, pB1b, wB0, wB1)
  }

  // epilogue: denominators + scale + relu + store
  float rt = rsum;
  rt += __shfl_xor(rt, 16, 64);
  rt += __shfl_xor(rt, 32, 64);
  float* ob = out + ((size_t)b * V + i0) * D + dh * 64 + (lane & 15);
#pragma unroll
  for (int r = 0; r < 4; ++r) {
    const int q = kq * 4 + r;
    const float inv_ = 1.0f / __shfl(rt, q, 64);
#pragma unroll
    for (int nt = 0; nt < 4; ++nt) {
      const float v = acc[nt][r] * inv_;
      ob[(size_t)q * D + nt * 16] = fmaxf(v, 0.f);
    }
  }
}

extern "C" void kernel_launch(void* const* d_in, const int* in_sizes, int n_in,
                              void* d_out, int out_size, void* d_ws, size_t ws_size,
                              hipStream_t stream) {
  const float* x = (const float*)d_in[0];
  const int* adj = (const int*)d_in[1];
  const float* W = (const float*)d_in[2];
  const float* a = (const float*)d_in[3];
  float* out = (float*)d_out;

  char* ws = (char*)d_ws;
  __hip_bfloat16* pTf = (__hip_bfloat16*)ws;                       // 4 MB
  float* ei = (float*)(ws + (4u << 20));                           // 64 KB
  float* Fj = (float*)(ws + (4u << 20) + 65536);                   // 64 KB
  float* Fp = (float*)(ws + (4u << 20) + 131072);                  // 64 KB
  unsigned int* adjp = (unsigned int*)(ws + (4u << 20) + 196608);  // 512 KB
  float* Wt = (float*)(ws + (4u << 20) + 196608 + 524288);         // 128 KB

  k_pack<<<dim3(V + D), dim3(256), 0, stream>>>(adj, W, adjp, Wt);
  k_proj<<<dim3(BATCH * (V / 32)), dim3(256), 0, stream>>>(x, Wt, a, pTf, ei, Fj, Fp);
  k_attn<<<dim3(BATCH * 2 * (V / 64)), dim3(256), 0, stream>>>(pTf, ei, Fj, Fp, adjp, out);
}

// Round 9
// 58.510 us; speedup vs baseline: 1.2395x; 1.2395x over previous
//
#include <hip/hip_runtime.h>
#include <hip/hip_bf16.h>

#define BATCH 8
#define V 2048
#define H 256
#define D 128

typedef __attribute__((ext_vector_type(8))) _Float16 f16x8;
typedef __attribute__((ext_vector_type(4))) float f32x4;
typedef unsigned int uint32;

static __device__ __forceinline__ uint32 pk2(float lo, float hi) {
  __fp16 __attribute__((ext_vector_type(2))) h = __builtin_amdgcn_cvt_pkrtz(lo, hi);
  uint32 u;
  __builtin_memcpy(&u, &h, 4);
  return u;
}

// -------- K_pack: adj -> bitmask words [V][64]; plus W -> Wt (transpose) --------
__global__ __launch_bounds__(256) void k_pack(const int* __restrict__ adj,
                                              const float* __restrict__ W,
                                              unsigned int* __restrict__ pk,
                                              float* __restrict__ Wt) {
  const int blk = blockIdx.x;
  if (blk < V) {
    const int w = threadIdx.x >> 6, lane = threadIdx.x & 63;
    const int* row = adj + (size_t)blk * V;
#pragma unroll
    for (int it = 0; it < 8; ++it) {
      const int j = it * 256 + w * 64 + lane;
      unsigned long long m = __ballot(row[j] != 0);
      if (lane < 2)
        pk[blk * 64 + it * 8 + w * 2 + lane] = (unsigned int)(m >> (lane * 32));
    }
  } else {
    const int d = blk - V;  // 0..127
    Wt[(size_t)threadIdx.x * D + d] = W[(size_t)d * H + threadIdx.x];
  }
}

// -------- K_proj: p = x @ W^T (fp32), fused e_i + f16 exp tables + f16 frag store --------
__global__ __launch_bounds__(256, 2) void k_proj(const float* __restrict__ x,
                                                 const float* __restrict__ Wt,
                                                 const float* __restrict__ a,
                                                 _Float16* __restrict__ pTf,
                                                 float* __restrict__ ei,
                                                 _Float16* __restrict__ Fh,
                                                 _Float16* __restrict__ Ph) {
  __shared__ float xs[32 * H];        // 32 KB
  __shared__ _Float16 st[128][52];    // 13 KB, padded
  const int t = threadIdx.x;
  const int b = blockIdx.x >> 6;
  const int j0 = (blockIdx.x & 63) * 32;
  {
    const float4* xsrc = (const float4*)(x + ((size_t)b * V + j0) * H);
    float4* xdst = (float4*)xs;
#pragma unroll
    for (int q = 0; q < 8; ++q) xdst[t + 256 * q] = xsrc[t + 256 * q];
  }
  __syncthreads();

  const int dq = t & 31;  // d quad: d = dq*4+dd
  const int jg = t >> 5;  // rows jg*4+k
  float acc[4][4];        // [k(row)][dd(col)]
#pragma unroll
  for (int k = 0; k < 4; ++k)
#pragma unroll
    for (int dd = 0; dd < 4; ++dd) acc[k][dd] = 0.f;

  const float* wbase = Wt + dq * 4;
  const float* xbase = xs + jg * 4 * H;
#pragma unroll 2
  for (int h4 = 0; h4 < 64; ++h4) {
    float4 wv[4], xv[4];
#pragma unroll
    for (int hh = 0; hh < 4; ++hh)
      wv[hh] = *(const float4*)(wbase + (size_t)(h4 * 4 + hh) * D);
#pragma unroll
    for (int k = 0; k < 4; ++k)
      xv[k] = *(const float4*)(xbase + k * H + h4 * 4);
#pragma unroll
    for (int k = 0; k < 4; ++k)
#pragma unroll
      for (int dd = 0; dd < 4; ++dd)
        acc[k][dd] += xv[k].x * ((const float*)&wv[0])[dd] +
                      xv[k].y * ((const float*)&wv[1])[dd] +
                      xv[k].z * ((const float*)&wv[2])[dd] +
                      xv[k].w * ((const float*)&wv[3])[dd];
  }

  // e_i / e_j from fp32 accumulators (reduce over dq lanes); f16 exp tables
  const float4 aLv = *(const float4*)(a + dq * 4);
  const float4 aRv = *(const float4*)(a + D + dq * 4);
#pragma unroll
  for (int k = 0; k < 4; ++k) {
    float te = acc[k][0] * aLv.x + acc[k][1] * aLv.y + acc[k][2] * aLv.z + acc[k][3] * aLv.w;
    float tf = acc[k][0] * aRv.x + acc[k][1] * aRv.y + acc[k][2] * aRv.z + acc[k][3] * aRv.w;
#pragma unroll
    for (int off = 1; off < 32; off <<= 1) {
      te += __shfl_xor(te, off, 64);
      tf += __shfl_xor(tf, off, 64);
    }
    if (dq == 0) {
      const size_t row = (size_t)b * V + j0 + jg * 4 + k;
      ei[row] = te;
      Fh[row] = (_Float16)__expf(tf);
      Ph[row] = (_Float16)__expf(0.2f * tf);
    }
  }

  // f16 transpose into st: st[d][j_local]
#pragma unroll
  for (int dd = 0; dd < 4; ++dd) {
    union { uint32 u[2]; unsigned long long ll; } pk_;
    pk_.u[0] = pk2(acc[0][dd], acc[1][dd]);
    pk_.u[1] = pk2(acc[2][dd], acc[3][dd]);
    *(unsigned long long*)&st[dq * 4 + dd][jg * 4] = pk_.ll;
  }
  __syncthreads();

  // fragment store: pTf[b][c][dt][ks][lane][8]
  const int c = (blockIdx.x & 63) >> 1;
  const int ks = blockIdx.x & 1;
  const int lane = t & 63, g = t >> 6;
#pragma unroll
  for (int ff = 0; ff < 2; ++ff) {
    const int dt = ff * 4 + g;
    const int dR = dt * 16 + (lane & 15);
    const int jc = (lane >> 4) * 8;
    union { unsigned long long ll[2]; f16x8 v; } vv_;
    vv_.ll[0] = *(const unsigned long long*)&st[dR][jc];
    vv_.ll[1] = *(const unsigned long long*)&st[dR][jc + 4];
    *(f16x8*)((char*)pTf +
              (((((size_t)b * 32 + c) * 8 + dt) * 2 + ks) * 64 + lane) * 16) = vv_.v;
  }
}

// -------- K_attn: out = relu((w @ p) / rowsum), f16 MFMA, chain-split accs --------
// 10 independent MFMA accumulator chains/body; af pipelined 1 body ahead;
// packed-f16 WGEN (pk_mul/pk_max) + LDS mask LUT; rowsum via ones-column MFMA.

typedef union { uint4 v; uint32 u[4]; } U4;
typedef union { uint32 u[4]; f16x8 v; } AFu;
struct PFS {
  U4 FH0, FH1, PH0, PH1, M0, M1;
  AFu AF0, AF1;
  uint32 w0, w1;
};

#define PKMUL(d, a, b) asm("v_pk_mul_f16 %0, %1, %2" : "=v"(d) : "v"(a), "v"(b));
#define PKMAX(d, a, b) asm("v_pk_max_f16 %0, %1, %2" : "=v"(d) : "v"(a), "v"(b));

#define WGEN1(AF, FH_, PH_, MSK_)                        \
  {                                                      \
    _Pragma("unroll") for (int p_ = 0; p_ < 4; ++p_) {   \
      uint32 t0_, t1_;                                   \
      PKMUL(t0_, Ei2, (FH_).u[p_])                       \
      PKMUL(t1_, Eip2, (PH_).u[p_])                      \
      PKMAX(t0_, t0_, t1_)                               \
      (AF).u[p_] = t0_ & (MSK_).u[p_];                   \
    }                                                    \
  }

#define WGEN(S)                      \
  WGEN1(S.AF0, S.FH0, S.PH0, S.M0)   \
  WGEN1(S.AF1, S.FH1, S.PH1, S.M1)

#define LUTREAD(S)                          \
  S.M0.v = lut[(S.w0 >> kq8) & 0xFF];       \
  S.M1.v = lut[(S.w1 >> kq8) & 0xFF];

#define PFETCH(S, C)                                      \
  {                                                       \
    const char* f_ = fbase + (C) * 128 + kq16;            \
    const char* p_ = pbase + (C) * 128 + kq16;            \
    S.FH0.v = *(const uint4*)(f_);                        \
    S.FH1.v = *(const uint4*)(f_ + 64);                   \
    S.PH0.v = *(const uint4*)(p_);                        \
    S.PH1.v = *(const uint4*)(p_ + 64);                   \
    S.w0 = adjp[iRb + (C) * 2];                           \
    S.w1 = adjp[iRb + (C) * 2 + 1];                       \
  }

#define LOADB(BR, C)                                      \
  {                                                       \
    const char* g_ = gbase + (size_t)(C) * 16384;         \
    _Pragma("unroll") for (int q_ = 0; q_ < 8; ++q_)      \
      BR[q_] = *(const f16x8*)(g_ + q_ * 1024);           \
  }

#define DOMFMA(S, BX)                                                                  \
  _Pragma("unroll") for (int nt_ = 0; nt_ < 4; ++nt_) {                                \
    acc0[nt_] = __builtin_amdgcn_mfma_f32_16x16x32_f16(S.AF0.v, BX[2 * nt_], acc0[nt_], 0, 0, 0);     \
    acc1[nt_] = __builtin_amdgcn_mfma_f32_16x16x32_f16(S.AF1.v, BX[2 * nt_ + 1], acc1[nt_], 0, 0, 0); \
  }                                                                                    \
  accS0 = __builtin_amdgcn_mfma_f32_16x16x32_f16(S.AF0.v, onesv, accS0, 0, 0, 0);      \
  accS1 = __builtin_amdgcn_mfma_f32_16x16x32_f16(S.AF1.v, onesv, accS1, 0, 0, 0);

// full-rate body (no bounds guards): consume SX/BX for chunk C, build SY's af
// for chunk C+1, refill SX/BX with chunk C+2.
#define BODYF(C, SX, BX, SY)  \
  {                           \
    DOMFMA(SX, BX)            \
    LUTREAD(SY)               \
    WGEN(SY)                  \
    LOADB(BX, (C) + 2)        \
    PFETCH(SX, (C) + 2)       \
  }

__global__ __launch_bounds__(256, 2) void k_attn(
    const _Float16* __restrict__ pTf,
    const float* __restrict__ ei,
    const _Float16* __restrict__ Fht,
    const _Float16* __restrict__ Pht,
    const unsigned int* __restrict__ adjp,
    float* __restrict__ out) {
  __shared__ uint4 lut[256];  // adj-bit-pair -> f16x2 mask words
  {
    const int tb = threadIdx.x;
    const uint32 m0 = ((tb & 1) ? 0xFFFFu : 0u) | ((tb & 2) ? 0xFFFF0000u : 0u);
    const uint32 m1 = ((tb & 4) ? 0xFFFFu : 0u) | ((tb & 8) ? 0xFFFF0000u : 0u);
    const uint32 m2 = ((tb & 16) ? 0xFFFFu : 0u) | ((tb & 32) ? 0xFFFF0000u : 0u);
    const uint32 m3 = ((tb & 64) ? 0xFFFFu : 0u) | ((tb & 128) ? 0xFFFF0000u : 0u);
    lut[tb] = make_uint4(m0, m1, m2, m3);
  }
  __syncthreads();  // write-once LUT; read-only afterwards

  const int t = threadIdx.x, lane = t & 63, wave = t >> 6;
  // bijective XCD chunk swizzle (nwg=512, 64 per XCD)
  const int pay = (blockIdx.x & 7) * 64 + (blockIdx.x >> 3);
  const int bdh = pay >> 5;
  const int ig = pay & 31;
  const int b = bdh >> 1, dh = bdh & 1;
  const int i0 = ig * 64 + wave * 16;
  const int kq = lane >> 4;
  const int kq8 = kq * 8;
  const int kq16 = kq * 16;
  const int iR = i0 + (lane & 15);
  const int iRb = iR * 64;
  const float eiv = ei[(size_t)b * V + iR];
  const float Eif = __expf(eiv);
  const float Eipf = __expf(0.2f * eiv);
  const uint32 Ei2 = pk2(Eif, Eif);
  const uint32 Eip2 = pk2(Eipf, Eipf);
  const char* fbase = (const char*)(Fht + (size_t)b * V);
  const char* pbase = (const char*)(Pht + (size_t)b * V);
  const size_t fb0 = ((size_t)b * 32) * 16384 + (size_t)dh * 8192;
  const char* gbase = (const char*)pTf + fb0 + lane * 16;

  union { uint32 u[4]; f16x8 v; } ones_;
  ones_.u[0] = ones_.u[1] = ones_.u[2] = ones_.u[3] = 0x3C003C00u;
  const f16x8 onesv = ones_.v;

  f32x4 acc0[4], acc1[4];
#pragma unroll
  for (int nt = 0; nt < 4; ++nt) {
    acc0[nt] = (f32x4){0.f, 0.f, 0.f, 0.f};
    acc1[nt] = (f32x4){0.f, 0.f, 0.f, 0.f};
  }
  f32x4 accS0 = (f32x4){0.f, 0.f, 0.f, 0.f};
  f32x4 accS1 = (f32x4){0.f, 0.f, 0.f, 0.f};

  f16x8 bA[8], bB[8];
  PFS sA, sB;

  // prologue
  LOADB(bA, 0)
  LOADB(bB, 1)
  PFETCH(sA, 0)
  PFETCH(sB, 1)
  LUTREAD(sA)
  WGEN(sA)

  for (int c2 = 0; c2 < 15; ++c2) {
    const int c = c2 * 2;
    BODYF(c, sA, bA, sB)
    BODYF(c + 1, sB, bB, sA)
  }
  // tail: chunk 30 (build af for 31, no more loads), chunk 31 (MFMA only)
  {
    DOMFMA(sA, bA)
    LUTREAD(sB)
    WGEN(sB)
  }
  { DOMFMA(sB, bB) }

  // epilogue: denominators are in accS (ones-column MFMA), already lane-aligned
  float* ob = out + ((size_t)b * V + i0) * D + dh * 64 + (lane & 15);
#pragma unroll
  for (int r = 0; r < 4; ++r) {
    const float inv_ = 1.0f / (accS0[r] + accS1[r]);
#pragma unroll
    for (int nt = 0; nt < 4; ++nt) {
      const float v = (acc0[nt][r] + acc1[nt][r]) * inv_;
      ob[(size_t)(kq * 4 + r) * D + nt * 16] = fmaxf(v, 0.f);
    }
  }
}

extern "C" void kernel_launch(void* const* d_in, const int* in_sizes, int n_in,
                              void* d_out, int out_size, void* d_ws, size_t ws_size,
                              hipStream_t stream) {
  const float* x = (const float*)d_in[0];
  const int* adj = (const int*)d_in[1];
  const float* W = (const float*)d_in[2];
  const float* a = (const float*)d_in[3];
  float* out = (float*)d_out;

  char* ws = (char*)d_ws;
  _Float16* pTf = (_Float16*)ws;                                   // 4 MB
  float* ei = (float*)(ws + (4u << 20));                           // 64 KB
  _Float16* Fh = (_Float16*)(ws + (4u << 20) + 65536);             // 32 KB
  _Float16* Ph = (_Float16*)(ws + (4u << 20) + 98304);             // 32 KB
  unsigned int* adjp = (unsigned int*)(ws + (4u << 20) + 131072);  // 512 KB
  float* Wt = (float*)(ws + (4u << 20) + 131072 + 524288);         // 128 KB

  k_pack<<<dim3(V + D), dim3(256), 0, stream>>>(adj, W, adjp, Wt);
  k_proj<<<dim3(BATCH * (V / 32)), dim3(256), 0, stream>>>(x, Wt, a, pTf, ei, Fh, Ph);
  k_attn<<<dim3(BATCH * 2 * (V / 64)), dim3(256), 0, stream>>>(pTf, ei, Fh, Ph, adjp, out);
}